// Round 1
// baseline (972.882 us; speedup 1.0000x reference)
//
#include <hip/hip_runtime.h>
#include <hip/hip_bf16.h>
#include <math.h>

#define H 1024
#define L 128
#define B 256
#define V 32000

// ---------------------------------------------------------------------------
// Kernel 1: embedding gather + attention logits + softmax + weighted sum.
// One block per batch element. Writes xcat = [emb0, attn_applied] (B, 2H) to ws
// and attn_weights (B, L) to d_out.
// ---------------------------------------------------------------------------
__global__ __launch_bounds__(256) void attn_kernel(
    const int* __restrict__ input_ids,     // (B)
    const float* __restrict__ hidden,      // (B, H)
    const float* __restrict__ enc,         // (B, L, H)
    const float* __restrict__ emb_table,   // (V, H)
    const float* __restrict__ attn_w,      // (L, 2H)
    const float* __restrict__ attn_b,      // (L)
    float* __restrict__ xcat,              // (B, 2H) ws
    float* __restrict__ attn_weights_out)  // (B, L) -> d_out region
{
    __shared__ float s_e[H];
    __shared__ float s_h[H];
    __shared__ float s_part[256];
    __shared__ float s_w[L];
    __shared__ float s_wr[4];

    const int b = blockIdx.x;
    const int tid = threadIdx.x;

    const int id = input_ids[b];
    const float4* e4 = (const float4*)(emb_table + (size_t)id * H);
    const float4* h4 = (const float4*)(hidden + (size_t)b * H);
    float4* xcat4 = (float4*)(xcat + (size_t)b * 2 * H);

    float4 ev = e4[tid];   // 256 threads * 4 floats = 1024
    float4 hv = h4[tid];
    ((float4*)s_e)[tid] = ev;
    ((float4*)s_h)[tid] = hv;
    xcat4[tid] = ev;       // emb0 half of xcat
    __syncthreads();

    // logits: thread t handles l = t&127, half = t>>7 (emb half or hidden half)
    const int l = tid & 127;
    const int half = tid >> 7;
    const float4* w4 = (const float4*)(attn_w + (size_t)l * (2 * H) + half * H);
    const float4* s4 = (const float4*)(half ? s_h : s_e);
    float acc = 0.f;
#pragma unroll 4
    for (int k = 0; k < H / 4; ++k) {
        float4 w = w4[k];
        float4 s = s4[k];
        acc += w.x * s.x + w.y * s.y + w.z * s.z + w.w * s.w;
    }
    s_part[tid] = acc;
    __syncthreads();
    if (tid < L) {
        s_w[tid] = s_part[tid] + s_part[tid + 128] + attn_b[tid];
    }
    __syncthreads();

    // softmax over s_w[0..127]
    const int wid = tid >> 6;
    float v = (tid < L) ? s_w[tid] : -INFINITY;
    for (int off = 32; off; off >>= 1) v = fmaxf(v, __shfl_xor(v, off));
    if ((tid & 63) == 0) s_wr[wid] = v;
    __syncthreads();
    const float m = fmaxf(s_wr[0], s_wr[1]);

    float e = 0.f;
    if (tid < L) e = __expf(s_w[tid] - m);
    float sv = e;
    for (int off = 32; off; off >>= 1) sv += __shfl_xor(sv, off);
    __syncthreads();
    if ((tid & 63) == 0) s_wr[wid] = sv;
    __syncthreads();
    const float inv = 1.f / (s_wr[0] + s_wr[1]);
    if (tid < L) {
        float w = e * inv;
        s_w[tid] = w;
        attn_weights_out[(size_t)b * L + tid] = w;
    }
    __syncthreads();

    // attn_applied[b][:] = sum_l w[l] * enc[b][l][:]
    const float4* enc4 = (const float4*)(enc + (size_t)b * L * H);
    float4 a = {0.f, 0.f, 0.f, 0.f};
#pragma unroll 4
    for (int ll = 0; ll < L; ++ll) {
        const float w = s_w[ll];
        float4 e2 = enc4[(size_t)ll * (H / 4) + tid];
        a.x += w * e2.x; a.y += w * e2.y; a.z += w * e2.z; a.w += w * e2.w;
    }
    xcat4[H / 4 + tid] = a;  // attn_applied half of xcat
}

// ---------------------------------------------------------------------------
// Tiled fp32 GEMM: C = act(A @ Wt^T + bias).  A: (M,K) row-major, Wt: (N,K)
// row-major (i.e. we compute A @ Wt.T).  64x64 tile, 256 threads, 4x4 micro.
// ---------------------------------------------------------------------------
#define TM 64
#define TN 64
#define TK 16

__global__ __launch_bounds__(256) void gemm_bias_kernel(
    const float* __restrict__ A,
    const float* __restrict__ Wt,
    const float* __restrict__ bias,
    float* __restrict__ C,
    int M, int N, int K, int relu)
{
    __shared__ float sA[TK][TM + 4];
    __shared__ float sW[TK][TN + 4];

    const int tid = threadIdx.x;
    const int bm = blockIdx.y * TM;
    const int bn = blockIdx.x * TN;
    const int tx = tid & 15;   // n dir
    const int ty = tid >> 4;   // m dir
    const int lr = tid >> 2;         // 0..63 row within tile
    const int lc = (tid & 3) * 4;    // 0,4,8,12

    float acc[4][4] = {};

    for (int k0 = 0; k0 < K; k0 += TK) {
        float4 av = *(const float4*)(A + (size_t)(bm + lr) * K + k0 + lc);
        float4 wv = *(const float4*)(Wt + (size_t)(bn + lr) * K + k0 + lc);
        sA[lc + 0][lr] = av.x; sA[lc + 1][lr] = av.y;
        sA[lc + 2][lr] = av.z; sA[lc + 3][lr] = av.w;
        sW[lc + 0][lr] = wv.x; sW[lc + 1][lr] = wv.y;
        sW[lc + 2][lr] = wv.z; sW[lc + 3][lr] = wv.w;
        __syncthreads();
#pragma unroll
        for (int kk = 0; kk < TK; ++kk) {
            const float a0 = sA[kk][ty * 4 + 0];
            const float a1 = sA[kk][ty * 4 + 1];
            const float a2 = sA[kk][ty * 4 + 2];
            const float a3 = sA[kk][ty * 4 + 3];
            const float b0 = sW[kk][tx * 4 + 0];
            const float b1 = sW[kk][tx * 4 + 1];
            const float b2 = sW[kk][tx * 4 + 2];
            const float b3 = sW[kk][tx * 4 + 3];
            acc[0][0] += a0 * b0; acc[0][1] += a0 * b1; acc[0][2] += a0 * b2; acc[0][3] += a0 * b3;
            acc[1][0] += a1 * b0; acc[1][1] += a1 * b1; acc[1][2] += a1 * b2; acc[1][3] += a1 * b3;
            acc[2][0] += a2 * b0; acc[2][1] += a2 * b1; acc[2][2] += a2 * b2; acc[2][3] += a2 * b3;
            acc[3][0] += a3 * b0; acc[3][1] += a3 * b1; acc[3][2] += a3 * b2; acc[3][3] += a3 * b3;
        }
        __syncthreads();
    }

    const float bb0 = bias[bn + tx * 4 + 0];
    const float bb1 = bias[bn + tx * 4 + 1];
    const float bb2 = bias[bn + tx * 4 + 2];
    const float bb3 = bias[bn + tx * 4 + 3];
#pragma unroll
    for (int i = 0; i < 4; ++i) {
        float4 o;
        o.x = acc[i][0] + bb0;
        o.y = acc[i][1] + bb1;
        o.z = acc[i][2] + bb2;
        o.w = acc[i][3] + bb3;
        if (relu) {
            o.x = fmaxf(o.x, 0.f); o.y = fmaxf(o.y, 0.f);
            o.z = fmaxf(o.z, 0.f); o.w = fmaxf(o.w, 0.f);
        }
        *(float4*)(C + (size_t)(bm + ty * 4 + i) * N + bn + tx * 4) = o;
    }
}

// ---------------------------------------------------------------------------
// GRU gates: r = sig(xr+hr), z = sig(xz+hz), n = tanh(xn + r*hn),
// h_new = (1-z)*n + z*h0
// ---------------------------------------------------------------------------
__global__ __launch_bounds__(256) void gru_kernel(
    const float* __restrict__ gx,   // (B, 3H)
    const float* __restrict__ gh,   // (B, 3H)
    const float* __restrict__ h0,   // (B, H)
    float* __restrict__ h_new)      // (B, H) -> d_out region
{
    const int idx = blockIdx.x * 256 + threadIdx.x;  // 0 .. B*H-1
    const int b = idx >> 10;          // / H
    const int j = idx & (H - 1);      // % H
    const size_t base = (size_t)b * 3 * H;
    const float xr = gx[base + j];
    const float xz = gx[base + H + j];
    const float xn = gx[base + 2 * H + j];
    const float hr = gh[base + j];
    const float hz = gh[base + H + j];
    const float hn = gh[base + 2 * H + j];
    const float r = 1.f / (1.f + __expf(-(xr + hr)));
    const float z = 1.f / (1.f + __expf(-(xz + hz)));
    const float n = tanhf(xn + r * hn);
    h_new[idx] = (1.f - z) * n + z * h0[idx];
}

// ---------------------------------------------------------------------------
// log-softmax pass 1: per-row max and log-sum-exp over V
// ---------------------------------------------------------------------------
__global__ __launch_bounds__(256) void lse_kernel(
    const float* __restrict__ logits,  // (B, V)
    float* __restrict__ mlse)          // (B, 2)
{
    __shared__ float s_r[4];
    const int b = blockIdx.x;
    const int tid = threadIdx.x;
    const float* row = logits + (size_t)b * V;

    float m = -INFINITY;
    for (int v = tid; v < V; v += 256) m = fmaxf(m, row[v]);
    for (int off = 32; off; off >>= 1) m = fmaxf(m, __shfl_xor(m, off));
    if ((tid & 63) == 0) s_r[tid >> 6] = m;
    __syncthreads();
    m = fmaxf(fmaxf(s_r[0], s_r[1]), fmaxf(s_r[2], s_r[3]));
    __syncthreads();

    float s = 0.f;
    for (int v = tid; v < V; v += 256) s += __expf(row[v] - m);
    for (int off = 32; off; off >>= 1) s += __shfl_xor(s, off);
    if ((tid & 63) == 0) s_r[tid >> 6] = s;
    __syncthreads();
    if (tid == 0) {
        mlse[2 * b] = m;
        mlse[2 * b + 1] = logf(s_r[0] + s_r[1] + s_r[2] + s_r[3]);
    }
}

// log-softmax pass 2: logp = logit - m - lse  (in place on d_out)
__global__ __launch_bounds__(256) void lsub_kernel(
    float* __restrict__ logits,        // (B, V) in/out
    const float* __restrict__ mlse)    // (B, 2)
{
    const size_t idx = (size_t)blockIdx.x * 256 + threadIdx.x;
    const int b = (int)(idx / V);
    logits[idx] = logits[idx] - mlse[2 * b] - mlse[2 * b + 1];
}

// ---------------------------------------------------------------------------
extern "C" void kernel_launch(void* const* d_in, const int* in_sizes, int n_in,
                              void* d_out, int out_size, void* d_ws, size_t ws_size,
                              hipStream_t stream) {
    const int*   input_ids = (const int*)d_in[0];
    const float* hidden    = (const float*)d_in[1];
    const float* enc       = (const float*)d_in[2];
    const float* emb_table = (const float*)d_in[3];
    const float* attn_w    = (const float*)d_in[4];
    const float* attn_b    = (const float*)d_in[5];
    const float* comb_w    = (const float*)d_in[6];
    const float* comb_b    = (const float*)d_in[7];
    const float* w_ih      = (const float*)d_in[8];
    const float* b_ih      = (const float*)d_in[9];
    const float* w_hh      = (const float*)d_in[10];
    const float* b_hh      = (const float*)d_in[11];
    const float* out_w     = (const float*)d_in[12];
    const float* out_b     = (const float*)d_in[13];

    float* out = (float*)d_out;
    float* logp         = out;                        // (B, V)
    float* h_new        = out + (size_t)B * V;        // (B, H)
    float* attn_weights = h_new + (size_t)B * H;      // (B, L)

    float* ws   = (float*)d_ws;
    float* xcat = ws;                                  // B*2H = 524288
    float* gx   = xcat + (size_t)B * 2 * H;            // B*3H = 786432
    float* gh   = gx + (size_t)B * 3 * H;              // B*3H
    float* x    = gh + (size_t)B * 3 * H;              // B*H
    float* mlse = x + (size_t)B * H;                   // B*2

    // 1. attention
    attn_kernel<<<dim3(B), dim3(256), 0, stream>>>(
        input_ids, hidden, enc, emb_table, attn_w, attn_b, xcat, attn_weights);

    // 2. combine: x = relu(xcat @ comb_w.T + comb_b)   (256x2048 -> 1024)
    gemm_bias_kernel<<<dim3(H / TN, B / TM), dim3(256), 0, stream>>>(
        xcat, comb_w, comb_b, x, B, H, 2 * H, 1);

    // 3. gx = x @ w_ih.T + b_ih   (256x1024 -> 3072)
    gemm_bias_kernel<<<dim3(3 * H / TN, B / TM), dim3(256), 0, stream>>>(
        x, w_ih, b_ih, gx, B, 3 * H, H, 0);

    // 4. gh = h0 @ w_hh.T + b_hh
    gemm_bias_kernel<<<dim3(3 * H / TN, B / TM), dim3(256), 0, stream>>>(
        hidden, w_hh, b_hh, gh, B, 3 * H, H, 0);

    // 5. GRU gates -> h_new
    gru_kernel<<<dim3(B * H / 256), dim3(256), 0, stream>>>(gx, gh, hidden, h_new);

    // 6. logits = h_new @ out_w.T + out_b   (256x1024 -> 32000)
    gemm_bias_kernel<<<dim3(V / TN, B / TM), dim3(256), 0, stream>>>(
        h_new, out_w, out_b, logp, B, V, H, 0);

    // 7-8. log_softmax
    lse_kernel<<<dim3(B), dim3(256), 0, stream>>>(logp, mlse);
    lsub_kernel<<<dim3((int)((size_t)B * V / 256)), dim3(256), 0, stream>>>(logp, mlse);
}

// Round 2
// 589.152 us; speedup vs baseline: 1.6513x; 1.6513x over previous
//
#include <hip/hip_runtime.h>
#include <hip/hip_bf16.h>
#include <math.h>

#define H 1024
#define L 128
#define B 256
#define V 32000

typedef __attribute__((ext_vector_type(8))) short bf16x8;
typedef __attribute__((ext_vector_type(4))) float f32x4;

static __device__ __forceinline__ ushort f2bf(float f) {
    unsigned int u = __float_as_uint(f);
    u += 0x7fffu + ((u >> 16) & 1u);   // RNE (finite inputs)
    return (ushort)(u >> 16);
}

// ---------------------------------------------------------------------------
// Kernel 1: embedding gather + attention logits + softmax + weighted sum.
// One block per batch element. Writes xcat_b16 = [emb0, attn_applied] (B,2H)
// bf16 and h0_b16 (B,H) bf16 to ws; attn_weights (B,L) fp32 to d_out.
// ---------------------------------------------------------------------------
__global__ __launch_bounds__(256) void attn_kernel(
    const int* __restrict__ input_ids,
    const float* __restrict__ hidden,
    const float* __restrict__ enc,
    const float* __restrict__ emb_table,
    const float* __restrict__ attn_w,
    const float* __restrict__ attn_b,
    ushort* __restrict__ xcat_b16,         // (B, 2H) bf16
    ushort* __restrict__ h0_b16,           // (B, H) bf16
    float* __restrict__ attn_weights_out)  // (B, L)
{
    __shared__ float s_e[H];
    __shared__ float s_h[H];
    __shared__ float s_part[256];
    __shared__ float s_w[L];
    __shared__ float s_wr[4];

    const int b = blockIdx.x;
    const int tid = threadIdx.x;

    const int id = input_ids[b];
    const float4* e4 = (const float4*)(emb_table + (size_t)id * H);
    const float4* h4 = (const float4*)(hidden + (size_t)b * H);

    float4 ev = e4[tid];
    float4 hv = h4[tid];
    ((float4*)s_e)[tid] = ev;
    ((float4*)s_h)[tid] = hv;

    // emb half of xcat (bf16) + h0 bf16
    {
        uint2 p;
        p.x = (unsigned)f2bf(ev.x) | ((unsigned)f2bf(ev.y) << 16);
        p.y = (unsigned)f2bf(ev.z) | ((unsigned)f2bf(ev.w) << 16);
        *(uint2*)(xcat_b16 + (size_t)b * 2 * H + tid * 4) = p;
        uint2 q;
        q.x = (unsigned)f2bf(hv.x) | ((unsigned)f2bf(hv.y) << 16);
        q.y = (unsigned)f2bf(hv.z) | ((unsigned)f2bf(hv.w) << 16);
        *(uint2*)(h0_b16 + (size_t)b * H + tid * 4) = q;
    }
    __syncthreads();

    // logits
    const int l = tid & 127;
    const int half = tid >> 7;
    const float4* w4 = (const float4*)(attn_w + (size_t)l * (2 * H) + half * H);
    const float4* s4 = (const float4*)(half ? s_h : s_e);
    float acc = 0.f;
#pragma unroll 4
    for (int k = 0; k < H / 4; ++k) {
        float4 w = w4[k];
        float4 s = s4[k];
        acc += w.x * s.x + w.y * s.y + w.z * s.z + w.w * s.w;
    }
    s_part[tid] = acc;
    __syncthreads();
    if (tid < L) s_w[tid] = s_part[tid] + s_part[tid + 128] + attn_b[tid];
    __syncthreads();

    // softmax over s_w[0..127]
    const int wid = tid >> 6;
    float v = (tid < L) ? s_w[tid] : -INFINITY;
    for (int off = 32; off; off >>= 1) v = fmaxf(v, __shfl_xor(v, off));
    if ((tid & 63) == 0) s_wr[wid] = v;
    __syncthreads();
    const float m = fmaxf(s_wr[0], s_wr[1]);

    float e = 0.f;
    if (tid < L) e = __expf(s_w[tid] - m);
    float sv = e;
    for (int off = 32; off; off >>= 1) sv += __shfl_xor(sv, off);
    __syncthreads();
    if ((tid & 63) == 0) s_wr[wid] = sv;
    __syncthreads();
    const float inv = 1.f / (s_wr[0] + s_wr[1]);
    if (tid < L) {
        float w = e * inv;
        s_w[tid] = w;
        attn_weights_out[(size_t)b * L + tid] = w;
    }
    __syncthreads();

    // attn_applied = sum_l w[l] * enc[b][l][:]
    const float4* enc4 = (const float4*)(enc + (size_t)b * L * H);
    float4 a = {0.f, 0.f, 0.f, 0.f};
#pragma unroll 4
    for (int ll = 0; ll < L; ++ll) {
        const float w = s_w[ll];
        float4 e2 = enc4[(size_t)ll * (H / 4) + tid];
        a.x += w * e2.x; a.y += w * e2.y; a.z += w * e2.z; a.w += w * e2.w;
    }
    {
        uint2 p;
        p.x = (unsigned)f2bf(a.x) | ((unsigned)f2bf(a.y) << 16);
        p.y = (unsigned)f2bf(a.z) | ((unsigned)f2bf(a.w) << 16);
        *(uint2*)(xcat_b16 + (size_t)b * 2 * H + H + tid * 4) = p;
    }
}

// ---------------------------------------------------------------------------
// bf16 MFMA GEMM: C = A(256,K bf16) @ W(N,K fp32->bf16).T + bias
// Block: M=256 x NT=32, 256 threads (4 waves, each 64 rows x 32 cols).
// MODE 0: write fp32      MODE 1: relu + write bf16
// MODE 2: rowsum[r] += sum_col exp(logit) (atomic), no C write
// MODE 3: write fp32 logp = logit - log(rowsum[row])
// ---------------------------------------------------------------------------
template<int K, int MODE>
__global__ __launch_bounds__(256) void mfma_gemm(
    const ushort* __restrict__ A,
    const float* __restrict__ W,
    const float* __restrict__ bias,
    float* __restrict__ outf,
    ushort* __restrict__ outb,
    float* __restrict__ rowsum,
    int N)
{
    constexpr int NT = 32;
    __shared__ ushort sA[256 * 72];   // rows padded to 72 bf16 (144 B)
    __shared__ ushort sW[NT * 72];
    __shared__ float sLse[256];

    const int tid = threadIdx.x;
    const int bn = blockIdx.x * NT;
    const int w = tid >> 6;
    const int l = tid & 63;
    const int g = l >> 4;
    const int ln = l & 15;
    const int trow = tid >> 3;   // 0..31
    const int tcol = tid & 7;    // 0..7

    if (MODE == 3) sLse[tid] = __logf(rowsum[tid]);

    f32x4 acc[4][2];
#pragma unroll
    for (int i = 0; i < 4; ++i)
#pragma unroll
        for (int n = 0; n < 2; ++n)
            acc[i][n] = (f32x4){0.f, 0.f, 0.f, 0.f};

    for (int k0 = 0; k0 < K; k0 += 64) {
        // stage A: 256 rows x 64 k (bf16), 8 passes of 32 rows
#pragma unroll
        for (int p = 0; p < 8; ++p) {
            const int r = p * 32 + trow;
            uint4 v = *(const uint4*)(A + (size_t)r * K + k0 + tcol * 8);
            *(uint4*)(sA + r * 72 + tcol * 8) = v;
        }
        // stage W: 32 rows x 64 k, fp32 -> bf16
        {
            const float* wp = W + (size_t)(bn + trow) * K + k0 + tcol * 8;
            float4 w0 = *(const float4*)(wp);
            float4 w1 = *(const float4*)(wp + 4);
            ushort tmp[8];
            tmp[0] = f2bf(w0.x); tmp[1] = f2bf(w0.y); tmp[2] = f2bf(w0.z); tmp[3] = f2bf(w0.w);
            tmp[4] = f2bf(w1.x); tmp[5] = f2bf(w1.y); tmp[6] = f2bf(w1.z); tmp[7] = f2bf(w1.w);
            *(uint4*)(sW + trow * 72 + tcol * 8) = *(const uint4*)tmp;
        }
        __syncthreads();
#pragma unroll
        for (int s = 0; s < 2; ++s) {
            bf16x8 af[4], bfr[2];
#pragma unroll
            for (int i = 0; i < 4; ++i)
                af[i] = *(const bf16x8*)(sA + (64 * w + 16 * i + ln) * 72 + s * 32 + g * 8);
#pragma unroll
            for (int n = 0; n < 2; ++n)
                bfr[n] = *(const bf16x8*)(sW + (16 * n + ln) * 72 + s * 32 + g * 8);
#pragma unroll
            for (int i = 0; i < 4; ++i)
#pragma unroll
                for (int n = 0; n < 2; ++n)
                    acc[i][n] = __builtin_amdgcn_mfma_f32_16x16x32_bf16(af[i], bfr[n], acc[i][n], 0, 0, 0);
        }
        __syncthreads();
    }

    const float b0 = bias[bn + ln];
    const float b1 = bias[bn + 16 + ln];

    if (MODE == 0) {
#pragma unroll
        for (int i = 0; i < 4; ++i)
#pragma unroll
            for (int n = 0; n < 2; ++n)
#pragma unroll
                for (int r = 0; r < 4; ++r)
                    outf[(size_t)(64 * w + 16 * i + 4 * g + r) * N + bn + 16 * n + ln] =
                        acc[i][n][r] + (n ? b1 : b0);
    } else if (MODE == 1) {
#pragma unroll
        for (int i = 0; i < 4; ++i)
#pragma unroll
            for (int n = 0; n < 2; ++n)
#pragma unroll
                for (int r = 0; r < 4; ++r) {
                    float vv = acc[i][n][r] + (n ? b1 : b0);
                    vv = fmaxf(vv, 0.f);
                    outb[(size_t)(64 * w + 16 * i + 4 * g + r) * N + bn + 16 * n + ln] = f2bf(vv);
                }
    } else if (MODE == 2) {
#pragma unroll
        for (int i = 0; i < 4; ++i) {
            float e[4];
#pragma unroll
            for (int r = 0; r < 4; ++r)
                e[r] = __expf(acc[i][0][r] + b0) + __expf(acc[i][1][r] + b1);
#pragma unroll
            for (int msk = 1; msk < 16; msk <<= 1)
#pragma unroll
                for (int r = 0; r < 4; ++r)
                    e[r] += __shfl_xor(e[r], msk);
            if (ln < 4)
                atomicAdd(&rowsum[64 * w + 16 * i + 4 * g + ln], e[ln]);
        }
    } else {  // MODE 3
#pragma unroll
        for (int i = 0; i < 4; ++i)
#pragma unroll
            for (int n = 0; n < 2; ++n)
#pragma unroll
                for (int r = 0; r < 4; ++r) {
                    const int row = 64 * w + 16 * i + 4 * g + r;
                    outf[(size_t)row * N + bn + 16 * n + ln] =
                        acc[i][n][r] + (n ? b1 : b0) - sLse[row];
                }
    }
}

// ---------------------------------------------------------------------------
// GRU gates; also emits h_new in bf16 and zeroes rowsum (block 0).
// ---------------------------------------------------------------------------
__global__ __launch_bounds__(256) void gru_kernel(
    const float* __restrict__ gx,
    const float* __restrict__ gh,
    const float* __restrict__ h0,
    float* __restrict__ h_new,
    ushort* __restrict__ hn_b16,
    float* __restrict__ rowsum)
{
    if (blockIdx.x == 0) rowsum[threadIdx.x] = 0.f;
    const int idx = blockIdx.x * 256 + threadIdx.x;
    const int b = idx >> 10;
    const int j = idx & (H - 1);
    const size_t base = (size_t)b * 3 * H;
    const float xr = gx[base + j];
    const float xz = gx[base + H + j];
    const float xn = gx[base + 2 * H + j];
    const float hr = gh[base + j];
    const float hz = gh[base + H + j];
    const float hn = gh[base + 2 * H + j];
    const float r = 1.f / (1.f + __expf(-(xr + hr)));
    const float z = 1.f / (1.f + __expf(-(xz + hz)));
    const float n = tanhf(xn + r * hn);
    const float out = (1.f - z) * n + z * h0[idx];
    h_new[idx] = out;
    hn_b16[idx] = f2bf(out);
}

// ---------------------------------------------------------------------------
extern "C" void kernel_launch(void* const* d_in, const int* in_sizes, int n_in,
                              void* d_out, int out_size, void* d_ws, size_t ws_size,
                              hipStream_t stream) {
    const int*   input_ids = (const int*)d_in[0];
    const float* hidden    = (const float*)d_in[1];
    const float* enc       = (const float*)d_in[2];
    const float* emb_table = (const float*)d_in[3];
    const float* attn_w    = (const float*)d_in[4];
    const float* attn_b    = (const float*)d_in[5];
    const float* comb_w    = (const float*)d_in[6];
    const float* comb_b    = (const float*)d_in[7];
    const float* w_ih      = (const float*)d_in[8];
    const float* b_ih      = (const float*)d_in[9];
    const float* w_hh      = (const float*)d_in[10];
    const float* b_hh      = (const float*)d_in[11];
    const float* out_w     = (const float*)d_in[12];
    const float* out_b     = (const float*)d_in[13];

    float* out = (float*)d_out;
    float* logp         = out;                    // (B, V)
    float* h_new        = out + (size_t)B * V;    // (B, H)
    float* attn_weights = h_new + (size_t)B * H;  // (B, L)

    // workspace layout
    ushort* xcat_b16 = (ushort*)d_ws;                          // B*2H
    ushort* h0_b16   = xcat_b16 + (size_t)B * 2 * H;           // B*H
    ushort* x_b16    = h0_b16 + (size_t)B * H;                 // B*H
    ushort* hn_b16   = x_b16 + (size_t)B * H;                  // B*H
    float*  gx       = (float*)(hn_b16 + (size_t)B * H);       // B*3H
    float*  gh       = gx + (size_t)B * 3 * H;                 // B*3H
    float*  rowsum   = gh + (size_t)B * 3 * H;                 // B

    // 1. attention (+ bf16 casts of emb/attn concat and h0)
    attn_kernel<<<dim3(B), dim3(256), 0, stream>>>(
        input_ids, hidden, enc, emb_table, attn_w, attn_b,
        xcat_b16, h0_b16, attn_weights);

    // 2. x = relu(xcat @ comb_w.T + comb_b) -> bf16   (N=1024)
    mfma_gemm<2 * H, 1><<<dim3(H / 32), dim3(256), 0, stream>>>(
        xcat_b16, comb_w, comb_b, nullptr, x_b16, nullptr, H);

    // 3. gx = x @ w_ih.T + b_ih   (N=3072)
    mfma_gemm<H, 0><<<dim3(3 * H / 32), dim3(256), 0, stream>>>(
        x_b16, w_ih, b_ih, gx, nullptr, nullptr, 3 * H);

    // 4. gh = h0 @ w_hh.T + b_hh
    mfma_gemm<H, 0><<<dim3(3 * H / 32), dim3(256), 0, stream>>>(
        h0_b16, w_hh, b_hh, gh, nullptr, nullptr, 3 * H);

    // 5. GRU gates -> h_new (fp32 + bf16), zero rowsum
    gru_kernel<<<dim3(B * H / 256), dim3(256), 0, stream>>>(
        gx, gh, hidden, h_new, hn_b16, rowsum);

    // 6. V-GEMM pass 1: rowsum[b] = sum_v exp(logit)
    mfma_gemm<H, 2><<<dim3(V / 32), dim3(256), 0, stream>>>(
        hn_b16, out_w, out_b, nullptr, nullptr, rowsum, V);

    // 7. V-GEMM pass 2: logp = logit - log(rowsum)
    mfma_gemm<H, 3><<<dim3(V / 32), dim3(256), 0, stream>>>(
        hn_b16, out_w, out_b, logp, nullptr, rowsum, V);
}